// Round 12
// baseline (4233.526 us; speedup 1.0000x reference)
//
#include <hip/hip_runtime.h>
#include <stdint.h>

#define B_ 4096
#define T_ 80
#define E_ 100
#define V_ 10000
#define U_ 1024

typedef unsigned short u16;
typedef __attribute__((ext_vector_type(8))) __bf16 bf16x8;
typedef __attribute__((ext_vector_type(4))) float f32x4;

__device__ __forceinline__ float bf2f(u16 u) {
    union { unsigned int i; float f; } v; v.i = ((unsigned int)u) << 16; return v.f;
}
__device__ __forceinline__ u16 f2bf(float f) {
    union { float f; unsigned int i; } v; v.f = f;
    unsigned int x = v.i;
    return (u16)((x + 0x7fffu + ((x >> 16) & 1u)) >> 16);
}

// async global->LDS, 16 B per lane; LDS dest = wave-uniform base + lane*16 (m104 semantics).
__device__ __forceinline__ void load16(const void* g, void* l) {
    __builtin_amdgcn_global_load_lds(
        (__attribute__((address_space(1))) void*)(uintptr_t)g,
        (__attribute__((address_space(3))) void*)(uint32_t)(uintptr_t)l,
        16, 0, 0);
}

// Pack weight src (f32, [K][N] row-major) into MFMA-B-fragment order, bf16, K padded to Kp:
// frag (n_blk, k_blk) = 1 KB holding lane l's 8 elems at [n = n_blk*16 + (l&15)]
// [k = k_blk*32 + (l>>4)*8 + j]. A wave's B-frag load = one coalesced global_load_dwordx4.
__global__ void frag_pack(const float* __restrict__ src, u16* __restrict__ dst,
                          int K, int N, int Kp)
{
    const int id = blockIdx.x * 256 + threadIdx.x;    // over N/16 * Kp/32 * 512 elems
    const int frag = id >> 9, within = id & 511;
    const int lane = within >> 3, j = within & 7;
    const int KPB = Kp >> 5;
    const int n_blk = frag / KPB, k_blk = frag % KPB;
    const int n = n_blk * 16 + (lane & 15);
    const int k = k_blk * 32 + (lane >> 4) * 8 + j;
    dst[id] = (k < K) ? f2bf(src[(size_t)k * N + n]) : (u16)0;
}

__global__ void embed_pad(const float* __restrict__ emb, u16* __restrict__ dst)
{
    int id = blockIdx.x * 256 + threadIdx.x;
    int v = id >> 7, k = id & 127;
    dst[id] = (k < E_) ? f2bf(emb[v * E_ + k]) : (u16)0;
}

// Fused phase p (independent sub-steps):
//   layer0: h0[p]   = tanh(embP[idx_p] @ Wx0 + h0[p-1] @ Wh0 + b0)   (if do0)
//   layer1: h1[p-1] = tanh(h0[p-1] @ Wx1 + h1[p-2] @ Wh1 + b1)       (if do1)
// Tile M=128 x N=128 (wave 64x64, 4x4 frags), BK=64. A through LDS (dbuf 2x16 KB,
// r6-proven XOR swizzle, 0 conflicts). B (weights) read DIRECT from global in
// fragment-packed order (1 coalesced dwordx4 per frag) — halves LDS traffic, the
// r11-measured dominant pipe. B loads issued BEFORE stage(u+1)'s A-DMA so the
// compiler's wait-for-B is vmcnt(4), leaving the A prefetch in flight.
__global__ void __launch_bounds__(256, 2)
rnn_phase(const u16* __restrict__ embP, const int* __restrict__ idx,
          const u16* __restrict__ Wx0F, const u16* __restrict__ Wh0F, const float* __restrict__ b0,
          const u16* __restrict__ Wx1F, const u16* __restrict__ Wh1F, const float* __restrict__ b1,
          const u16* __restrict__ h0r, u16* __restrict__ h0w,
          const u16* __restrict__ h1r, u16* __restrict__ h1w,
          int do0, int do1)
{
    const int layer = blockIdx.y & 1;
    if (layer ? !do1 : !do0) return;

    __shared__ u16 As[2][128 * 64];   // 2 x 16 KB (A only)
    const int tid  = threadIdx.x;
    const int lane = tid & 63;
    const int wave = tid >> 6;
    const int wm = wave >> 1, wn = wave & 1;
    const int m0 = blockIdx.x * 128;
    const int n0 = (blockIdx.y >> 1) * 128;

    const u16 *A1, *W1f, *A2, *W2f; const float* bias; u16* C; int K1; bool gather;
    if (layer == 0) { A1 = embP; W1f = Wx0F; K1 = 128;  gather = true;  A2 = h0r; W2f = Wh0F; bias = b0; C = h0w; }
    else            { A1 = h0r;  W1f = Wx1F; K1 = 1024; gather = false; A2 = h1r; W2f = Wh1F; bias = b1; C = h1w; }
    const int KB1  = K1 >> 6;           // 64-wide K blocks in the first segment
    const int TOT  = KB1 + (U_ >> 6);
    const int KPB1 = K1 >> 5;           // 32-wide frag k-blocks, first segment
    const int KPB2 = U_ >> 5;           // = 32, second segment

    // A staging: per wave rows [wave*32,+32) in 4 calls; lane -> row += lane>>3, chunk lane&7,
    // source col chunk swizzled (lane&7)^(row&7).
    const int r8 = lane >> 3;
    const int c8 = lane & 7;

    int gv[4];
    if (gather) {
#pragma unroll
        for (int cc = 0; cc < 4; cc++)
            gv[cc] = idx[(size_t)(m0 + wave * 32 + cc * 8 + r8) * T_];
    }

    const f32x4 z = {0.f, 0.f, 0.f, 0.f};
    f32x4 acc[4][4];
#pragma unroll
    for (int i = 0; i < 4; i++)
#pragma unroll
        for (int j = 0; j < 4; j++) acc[i][j] = z;

    // loop-invariant A fragment read offsets (u16 elems), inverse-swizzled
    const int l15 = lane & 15, q = lane >> 4, l7 = lane & 7;
    int offA[2][4];
#pragma unroll
    for (int kk = 0; kk < 2; kk++)
#pragma unroll
        for (int f = 0; f < 4; f++) {
            const int rA = wm * 64 + f * 16 + l15;
            offA[kk][f] = rA * 64 + (((kk * 4 + q) ^ l7) * 8);
        }

    // B fragment bases: wave's n-frags are n_blk = n0/16 + wn*4 + f; elem addr =
    // (n_blk * KPB + k_blk) * 512 + lane*8
    const int nb = (n0 >> 4) + wn * 4;

    auto stage = [&](int u, int p) {
        u16* Ad = As[p] + wave * 2048;   // 32 rows x 64 elems
        if (u < KB1) {
            const int k0 = u * 64;
#pragma unroll
            for (int cc = 0; cc < 4; cc++) {
                const int row = wave * 32 + cc * 8 + r8;
                const int scw = (c8 ^ (row & 7)) * 8;
                const u16* ap = gather ? A1 + (size_t)gv[cc] * 128 + k0 + scw
                                       : A1 + (size_t)(m0 + row) * K1 + k0 + scw;
                load16(ap, Ad + cc * 512);
            }
        } else {
            const int k0 = (u - KB1) * 64;
#pragma unroll
            for (int cc = 0; cc < 4; cc++) {
                const int row = wave * 32 + cc * 8 + r8;
                const int scw = (c8 ^ (row & 7)) * 8;
                load16(A2 + (size_t)(m0 + row) * U_ + k0 + scw, Ad + cc * 512);
            }
        }
    };

    stage(0, 0);

#pragma unroll 1
    for (int u = 0; u < TOT; ++u) {
        const int p = u & 1;
        __syncthreads();                 // drains vmcnt -> As[p] ready
        // B-frag loads FIRST (so their waitcnt leaves the A-DMA below outstanding)
        bf16x8 b[2][4];
        {
            const u16* Wf; int kb; int KPB;
            if (u < KB1) { Wf = W1f; kb = u * 2;          KPB = KPB1; }
            else         { Wf = W2f; kb = (u - KB1) * 2;  KPB = KPB2; }
#pragma unroll
            for (int kk = 0; kk < 2; kk++)
#pragma unroll
                for (int f = 0; f < 4; f++)
                    b[kk][f] = *reinterpret_cast<const bf16x8*>(
                        Wf + ((size_t)(nb + f) * KPB + kb + kk) * 512 + lane * 8);
        }
        if (u + 1 < TOT) stage(u + 1, p ^ 1);   // A-DMA in flight during compute
#pragma unroll
        for (int kk = 0; kk < 2; kk++) {
            bf16x8 a[4];
#pragma unroll
            for (int f = 0; f < 4; f++)
                a[f] = *reinterpret_cast<const bf16x8*>(As[p] + offA[kk][f]);
#pragma unroll
            for (int i = 0; i < 4; i++)
#pragma unroll
                for (int j = 0; j < 4; j++)
                    acc[i][j] = __builtin_amdgcn_mfma_f32_16x16x32_bf16(a[i], b[kk][j], acc[i][j], 0, 0, 0);
        }
    }

    // epilogue: bias + tanh, bf16 store (C/D map: col = lane&15, row = (lane>>4)*4 + reg)
#pragma unroll
    for (int j = 0; j < 4; j++) {
        const int col = n0 + wn * 64 + j * 16 + l15;
        const float bv = bias[col];
#pragma unroll
        for (int i = 0; i < 4; i++) {
#pragma unroll
            for (int r = 0; r < 4; r++) {
                const int row = m0 + wm * 64 + i * 16 + (q << 2) + r;
                float x = acc[i][j][r] + bv;
                x = fminf(15.f, fmaxf(-15.f, x));
                float e = __expf(2.f * x);
                C[(size_t)row * U_ + col] = f2bf((e - 1.f) / (e + 1.f));
            }
        }
    }
}

// out[b] = sigmoid( dot(h1[b,:], Wfc) + bfc ), one wave per row; f32 out
__global__ void final_dense(const u16* __restrict__ h1, const float* __restrict__ Wfc,
                            const float* __restrict__ bfc, float* __restrict__ out)
{
    const int lane = threadIdx.x & 63;
    const int wave = threadIdx.x >> 6;
    const int row = blockIdx.x * 4 + wave;
    const u16* hp = h1 + (size_t)row * U_ + lane * 16;
    const float* wp = Wfc + lane * 16;
    float s = 0.f;
#pragma unroll
    for (int i = 0; i < 16; i++) s += bf2f(hp[i]) * wp[i];
#pragma unroll
    for (int off = 32; off; off >>= 1) s += __shfl_down(s, off);
    if (lane == 0) {
        float x = s + bfc[0];
        out[row] = 1.f / (1.f + __expf(-x));
    }
}

extern "C" void kernel_launch(void* const* d_in, const int* in_sizes, int n_in,
                              void* d_out, int out_size, void* d_ws, size_t ws_size,
                              hipStream_t stream)
{
    const int*   inputs = (const int*)d_in[0];
    const float* emb    = (const float*)d_in[1];
    const float* Wx0    = (const float*)d_in[2];
    const float* Wh0    = (const float*)d_in[3];
    const float* b0     = (const float*)d_in[4];
    const float* Wx1    = (const float*)d_in[5];
    const float* Wh1    = (const float*)d_in[6];
    const float* b1     = (const float*)d_in[7];
    const float* Wfc    = (const float*)d_in[8];
    const float* bfc    = (const float*)d_in[9];

    char* ws = (char*)d_ws;
    const size_t MB = 1 << 20;
    u16* h0b[2] = { (u16*)(ws + 0 * MB), (u16*)(ws + 8 * MB) };   // 8 MB each
    u16* h1b[2] = { (u16*)(ws + 16 * MB), (u16*)(ws + 24 * MB) };
    u16* embP = (u16*)(ws + 32 * MB);  // 2.56 MB
    u16* Wx0F = (u16*)(ws + 35 * MB);  // frag-packed [64 n_blk][4 k_blk]  256 KB
    u16* Wh0F = (u16*)(ws + 36 * MB);  // [64][32] 2 MB
    u16* Wx1F = (u16*)(ws + 38 * MB);  // 2 MB
    u16* Wh1F = (u16*)(ws + 40 * MB);  // ..42 MB

    // phase 0 reads h0[-1] from h0b[1]; phase 1 reads h1[-1] from h1b[1]
    hipMemsetAsync(h0b[1], 0, 8 * MB, stream);
    hipMemsetAsync(h1b[1], 0, 8 * MB, stream);

    embed_pad<<<V_ * 128 / 256, 256, 0, stream>>>(emb, embP);
    frag_pack<<<(U_ / 16) * (128 / 32) * 512 / 256, 256, 0, stream>>>(Wx0, Wx0F, E_, U_, 128);
    frag_pack<<<(U_ / 16) * (U_ / 32) * 512 / 256, 256, 0, stream>>>(Wh0, Wh0F, U_, U_, U_);
    frag_pack<<<(U_ / 16) * (U_ / 32) * 512 / 256, 256, 0, stream>>>(Wx1, Wx1F, U_, U_, U_);
    frag_pack<<<(U_ / 16) * (U_ / 32) * 512 / 256, 256, 0, stream>>>(Wh1, Wh1F, U_, U_, U_);

    // phase p: layer0 writes h0[p] -> h0b[p&1], reads h0[p-1] -> h0b[(p&1)^1];
    //          layer1 writes h1[p-1] -> h1b[(p&1)^1], reads h1[p-2] -> h1b[p&1]
    dim3 grid(B_ / 128, 2 * (U_ / 128));   // 32 x 16 = 512 blocks -> 2/CU, all resident
    for (int p = 0; p <= T_; ++p) {
        const int e = p & 1;
        rnn_phase<<<grid, 256, 0, stream>>>(embP, inputs + p,
                                            Wx0F, Wh0F, b0, Wx1F, Wh1F, b1,
                                            h0b[e ^ 1], h0b[e], h1b[e], h1b[e ^ 1],
                                            (int)(p < T_), (int)(p >= 1));
    }
    // h1[79] written at phase 80 into h1b[(80&1)^1] = h1b[1]
    final_dense<<<B_ / 4, 256, 0, stream>>>(h1b[1], Wfc, bfc, (float*)d_out);
}

// Round 13
// 3245.279 us; speedup vs baseline: 1.3045x; 1.3045x over previous
//
#include <hip/hip_runtime.h>
#include <stdint.h>

#define B_ 4096
#define T_ 80
#define E_ 100
#define V_ 10000
#define U_ 1024

typedef unsigned short u16;
typedef __attribute__((ext_vector_type(8))) __bf16 bf16x8;
typedef __attribute__((ext_vector_type(4))) float f32x4;

__device__ __forceinline__ float bf2f(u16 u) {
    union { unsigned int i; float f; } v; v.i = ((unsigned int)u) << 16; return v.f;
}
__device__ __forceinline__ u16 f2bf(float f) {
    union { float f; unsigned int i; } v; v.f = f;
    unsigned int x = v.i;
    return (u16)((x + 0x7fffu + ((x >> 16) & 1u)) >> 16);
}

// async global->LDS, 16 B per lane; LDS dest = wave-uniform base + lane*16 (m104 semantics).
__device__ __forceinline__ void load16(const void* g, void* l) {
    __builtin_amdgcn_global_load_lds(
        (__attribute__((address_space(1))) void*)(uintptr_t)g,
        (__attribute__((address_space(3))) void*)(uint32_t)(uintptr_t)l,
        16, 0, 0);
}

// Pack weight src (f32, [K][N] row-major) into MFMA-B-fragment order, bf16, K padded to Kp:
// frag (n_blk, k_blk) = 1 KB holding lane l's 8 elems at [n = n_blk*16 + (l&15)]
// [k = k_blk*32 + (l>>4)*8 + j]. A wave's B-frag load = one coalesced global_load_dwordx4.
__global__ void frag_pack(const float* __restrict__ src, u16* __restrict__ dst,
                          int K, int N, int Kp)
{
    const int id = blockIdx.x * 256 + threadIdx.x;    // over N/16 * Kp/32 * 512 elems
    const int frag = id >> 9, within = id & 511;
    const int lane = within >> 3, j = within & 7;
    const int KPB = Kp >> 5;
    const int n_blk = frag / KPB, k_blk = frag % KPB;
    const int n = n_blk * 16 + (lane & 15);
    const int k = k_blk * 32 + (lane >> 4) * 8 + j;
    dst[id] = (k < K) ? f2bf(src[(size_t)k * N + n]) : (u16)0;
}

__global__ void embed_pad(const float* __restrict__ emb, u16* __restrict__ dst)
{
    int id = blockIdx.x * 256 + threadIdx.x;
    int v = id >> 7, k = id & 127;
    dst[id] = (k < E_) ? f2bf(emb[v * E_ + k]) : (u16)0;
}

// Fused phase p (independent sub-steps):
//   layer0: h0[p]   = tanh(embP[idx_p] @ Wx0 + h0[p-1] @ Wh0 + b0)   (if do0)
//   layer1: h1[p-1] = tanh(h0[p-1] @ Wx1 + h1[p-2] @ Wh1 + b1)       (if do1)
// Tile M=128 x N=128 (wave 64x64), BK=64. A through LDS dbuf (r6 XOR swizzle, 0
// conflicts). B (weights) from global in fragment-packed order, PIPELINED AT DISTANCE 1
// INTO REGISTERS: B(u+1) is issued at the top of iter u (with stage(u+1)'s A-DMA) and
// consumed at iter u+1, so its L2 latency is covered by compute(u) — fixes r12's
// exposed-latency regression while keeping its LDS-traffic halving (r11 was ~83%
// LDS-pipe-bound: 64 ds_read_b128 + 32 KB DMA-write per block-iter). Loop 2x-unrolled
// (TOT always even) to ping-pong the two B register sets with zero copies.
__global__ void __launch_bounds__(256, 2)
rnn_phase(const u16* __restrict__ embP, const int* __restrict__ idx,
          const u16* __restrict__ Wx0F, const u16* __restrict__ Wh0F, const float* __restrict__ b0,
          const u16* __restrict__ Wx1F, const u16* __restrict__ Wh1F, const float* __restrict__ b1,
          const u16* __restrict__ h0r, u16* __restrict__ h0w,
          const u16* __restrict__ h1r, u16* __restrict__ h1w,
          int do0, int do1)
{
    const int layer = blockIdx.y & 1;
    if (layer ? !do1 : !do0) return;

    __shared__ u16 As[2][128 * 64];   // 2 x 16 KB (A only)
    const int tid  = threadIdx.x;
    const int lane = tid & 63;
    const int wave = tid >> 6;
    const int wm = wave >> 1, wn = wave & 1;
    const int m0 = blockIdx.x * 128;
    const int n0 = (blockIdx.y >> 1) * 128;

    const u16 *A1, *W1f, *A2, *W2f; const float* bias; u16* C; int K1; bool gather;
    if (layer == 0) { A1 = embP; W1f = Wx0F; K1 = 128;  gather = true;  A2 = h0r; W2f = Wh0F; bias = b0; C = h0w; }
    else            { A1 = h0r;  W1f = Wx1F; K1 = 1024; gather = false; A2 = h1r; W2f = Wh1F; bias = b1; C = h1w; }
    const int KB1  = K1 >> 6;           // 64-wide K blocks in the first segment (2 or 16)
    const int TOT  = KB1 + (U_ >> 6);   // 18 or 32 — always even
    const int KPB1 = K1 >> 5;
    const int KPB2 = U_ >> 5;

    // A staging: per wave rows [wave*32,+32) in 4 calls; lane -> row += lane>>3,
    // chunk lane&7, source col chunk swizzled (lane&7)^(row&7).
    const int r8 = lane >> 3;
    const int c8 = lane & 7;

    int gv[4];
    if (gather) {
#pragma unroll
        for (int cc = 0; cc < 4; cc++)
            gv[cc] = idx[(size_t)(m0 + wave * 32 + cc * 8 + r8) * T_];
    }

    const f32x4 z = {0.f, 0.f, 0.f, 0.f};
    f32x4 acc[4][4];
#pragma unroll
    for (int i = 0; i < 4; i++)
#pragma unroll
        for (int j = 0; j < 4; j++) acc[i][j] = z;

    // loop-invariant A fragment read offsets (u16 elems), inverse-swizzled
    const int l15 = lane & 15, q = lane >> 4, l7 = lane & 7;
    int offA[2][4];
#pragma unroll
    for (int kk = 0; kk < 2; kk++)
#pragma unroll
        for (int f = 0; f < 4; f++) {
            const int rA = wm * 64 + f * 16 + l15;
            offA[kk][f] = rA * 64 + (((kk * 4 + q) ^ l7) * 8);
        }

    // B fragment bases: wave's n-frags are n_blk = n0/16 + wn*4 + f
    const int nb = (n0 >> 4) + wn * 4;

    auto stage = [&](int u, int p) {
        u16* Ad = As[p] + wave * 2048;   // 32 rows x 64 elems
        if (u < KB1) {
            const int k0 = u * 64;
#pragma unroll
            for (int cc = 0; cc < 4; cc++) {
                const int row = wave * 32 + cc * 8 + r8;
                const int scw = (c8 ^ (row & 7)) * 8;
                const u16* ap = gather ? A1 + (size_t)gv[cc] * 128 + k0 + scw
                                       : A1 + (size_t)(m0 + row) * K1 + k0 + scw;
                load16(ap, Ad + cc * 512);
            }
        } else {
            const int k0 = (u - KB1) * 64;
#pragma unroll
            for (int cc = 0; cc < 4; cc++) {
                const int row = wave * 32 + cc * 8 + r8;
                const int scw = (c8 ^ (row & 7)) * 8;
                load16(A2 + (size_t)(m0 + row) * U_ + k0 + scw, Ad + cc * 512);
            }
        }
    };

    auto loadB = [&](int u, bf16x8 bdst[2][4]) {
        const u16* Wf; int kb, KPB;
        if (u < KB1) { Wf = W1f; kb = u * 2;         KPB = KPB1; }
        else         { Wf = W2f; kb = (u - KB1) * 2; KPB = KPB2; }
#pragma unroll
        for (int kk = 0; kk < 2; kk++)
#pragma unroll
            for (int f = 0; f < 4; f++)
                bdst[kk][f] = *reinterpret_cast<const bf16x8*>(
                    Wf + ((size_t)(nb + f) * KPB + kb + kk) * 512 + lane * 8);
    };

    auto compute = [&](const u16* Ab, bf16x8 b[2][4]) {
#pragma unroll
        for (int kk = 0; kk < 2; kk++) {
            bf16x8 a[4];
#pragma unroll
            for (int f = 0; f < 4; f++)
                a[f] = *reinterpret_cast<const bf16x8*>(Ab + offA[kk][f]);
#pragma unroll
            for (int i = 0; i < 4; i++)
#pragma unroll
                for (int j = 0; j < 4; j++)
                    acc[i][j] = __builtin_amdgcn_mfma_f32_16x16x32_bf16(a[i], b[kk][j], acc[i][j], 0, 0, 0);
        }
    };

    bf16x8 bA[2][4], bB[2][4];
    stage(0, 0);
    loadB(0, bA);

#pragma unroll 1
    for (int u = 0; u < TOT; u += 2) {
        __syncthreads();                        // As[0] + bA(u) drained
        loadB(u + 1, bB);                       // in flight during compute(u)
        stage(u + 1, 1);
        compute(As[0], bA);
        __syncthreads();                        // As[1] + bB(u+1) drained
        if (u + 2 < TOT) {
            loadB(u + 2, bA);                   // in flight during compute(u+1)
            stage(u + 2, 0);
        }
        compute(As[1], bB);
    }

    // epilogue: bias + tanh, bf16 store (C/D map: col = lane&15, row = (lane>>4)*4 + reg)
#pragma unroll
    for (int j = 0; j < 4; j++) {
        const int col = n0 + wn * 64 + j * 16 + l15;
        const float bv = bias[col];
#pragma unroll
        for (int i = 0; i < 4; i++) {
#pragma unroll
            for (int r = 0; r < 4; r++) {
                const int row = m0 + wm * 64 + i * 16 + (q << 2) + r;
                float x = acc[i][j][r] + bv;
                x = fminf(15.f, fmaxf(-15.f, x));
                float e = __expf(2.f * x);
                C[(size_t)row * U_ + col] = f2bf((e - 1.f) / (e + 1.f));
            }
        }
    }
}

// out[b] = sigmoid( dot(h1[b,:], Wfc) + bfc ), one wave per row; f32 out
__global__ void final_dense(const u16* __restrict__ h1, const float* __restrict__ Wfc,
                            const float* __restrict__ bfc, float* __restrict__ out)
{
    const int lane = threadIdx.x & 63;
    const int wave = threadIdx.x >> 6;
    const int row = blockIdx.x * 4 + wave;
    const u16* hp = h1 + (size_t)row * U_ + lane * 16;
    const float* wp = Wfc + lane * 16;
    float s = 0.f;
#pragma unroll
    for (int i = 0; i < 16; i++) s += bf2f(hp[i]) * wp[i];
#pragma unroll
    for (int off = 32; off; off >>= 1) s += __shfl_down(s, off);
    if (lane == 0) {
        float x = s + bfc[0];
        out[row] = 1.f / (1.f + __expf(-x));
    }
}

extern "C" void kernel_launch(void* const* d_in, const int* in_sizes, int n_in,
                              void* d_out, int out_size, void* d_ws, size_t ws_size,
                              hipStream_t stream)
{
    const int*   inputs = (const int*)d_in[0];
    const float* emb    = (const float*)d_in[1];
    const float* Wx0    = (const float*)d_in[2];
    const float* Wh0    = (const float*)d_in[3];
    const float* b0     = (const float*)d_in[4];
    const float* Wx1    = (const float*)d_in[5];
    const float* Wh1    = (const float*)d_in[6];
    const float* b1     = (const float*)d_in[7];
    const float* Wfc    = (const float*)d_in[8];
    const float* bfc    = (const float*)d_in[9];

    char* ws = (char*)d_ws;
    const size_t MB = 1 << 20;
    u16* h0b[2] = { (u16*)(ws + 0 * MB), (u16*)(ws + 8 * MB) };   // 8 MB each
    u16* h1b[2] = { (u16*)(ws + 16 * MB), (u16*)(ws + 24 * MB) };
    u16* embP = (u16*)(ws + 32 * MB);  // 2.56 MB
    u16* Wx0F = (u16*)(ws + 35 * MB);  // frag-packed [64 n_blk][4 k_blk]  256 KB
    u16* Wh0F = (u16*)(ws + 36 * MB);  // [64][32] 2 MB
    u16* Wx1F = (u16*)(ws + 38 * MB);  // 2 MB
    u16* Wh1F = (u16*)(ws + 40 * MB);  // ..42 MB

    // phase 0 reads h0[-1] from h0b[1]; phase 1 reads h1[-1] from h1b[1]
    hipMemsetAsync(h0b[1], 0, 8 * MB, stream);
    hipMemsetAsync(h1b[1], 0, 8 * MB, stream);

    embed_pad<<<V_ * 128 / 256, 256, 0, stream>>>(emb, embP);
    frag_pack<<<(U_ / 16) * (128 / 32) * 512 / 256, 256, 0, stream>>>(Wx0, Wx0F, E_, U_, 128);
    frag_pack<<<(U_ / 16) * (U_ / 32) * 512 / 256, 256, 0, stream>>>(Wh0, Wh0F, U_, U_, U_);
    frag_pack<<<(U_ / 16) * (U_ / 32) * 512 / 256, 256, 0, stream>>>(Wx1, Wx1F, U_, U_, U_);
    frag_pack<<<(U_ / 16) * (U_ / 32) * 512 / 256, 256, 0, stream>>>(Wh1, Wh1F, U_, U_, U_);

    // phase p: layer0 writes h0[p] -> h0b[p&1], reads h0[p-1] -> h0b[(p&1)^1];
    //          layer1 writes h1[p-1] -> h1b[(p&1)^1], reads h1[p-2] -> h1b[p&1]
    dim3 grid(B_ / 128, 2 * (U_ / 128));   // 32 x 16 = 512 blocks -> 2/CU, all resident
    for (int p = 0; p <= T_; ++p) {
        const int e = p & 1;
        rnn_phase<<<grid, 256, 0, stream>>>(embP, inputs + p,
                                            Wx0F, Wh0F, b0, Wx1F, Wh1F, b1,
                                            h0b[e ^ 1], h0b[e], h1b[e], h1b[e ^ 1],
                                            (int)(p < T_), (int)(p >= 1));
    }
    // h1[79] written at phase 80 into h1b[(80&1)^1] = h1b[1]
    final_dense<<<B_ / 4, 256, 0, stream>>>(h1b[1], Wfc, bfc, (float*)d_out);
}

// Round 14
// 3068.898 us; speedup vs baseline: 1.3795x; 1.0575x over previous
//
#include <hip/hip_runtime.h>
#include <stdint.h>

#define B_ 4096
#define T_ 80
#define E_ 100
#define V_ 10000
#define U_ 1024

typedef unsigned short u16;
typedef __attribute__((ext_vector_type(8))) __bf16 bf16x8;
typedef __attribute__((ext_vector_type(4))) float f32x4;

__device__ __forceinline__ float bf2f(u16 u) {
    union { unsigned int i; float f; } v; v.i = ((unsigned int)u) << 16; return v.f;
}
__device__ __forceinline__ u16 f2bf(float f) {
    union { float f; unsigned int i; } v; v.f = f;
    unsigned int x = v.i;
    return (u16)((x + 0x7fffu + ((x >> 16) & 1u)) >> 16);
}

// async global->LDS, 16 B per lane; LDS dest = wave-uniform base + lane*16 (m104 semantics).
__device__ __forceinline__ void load16(const void* g, void* l) {
    __builtin_amdgcn_global_load_lds(
        (__attribute__((address_space(1))) void*)(uintptr_t)g,
        (__attribute__((address_space(3))) void*)(uint32_t)(uintptr_t)l,
        16, 0, 0);
}

// Pack weight src (f32, [K][N] row-major) into MFMA-B-fragment order, bf16, K padded to Kp:
// frag (n_blk, k_blk) = 1 KB holding lane l's 8 elems at [n = n_blk*16 + (l&15)]
// [k = k_blk*32 + (l>>4)*8 + j]. A wave's B-frag load = one coalesced global_load_dwordx4.
__global__ void frag_pack(const float* __restrict__ src, u16* __restrict__ dst,
                          int K, int N, int Kp)
{
    const int id = blockIdx.x * 256 + threadIdx.x;    // over N/16 * Kp/32 * 512 elems
    const int frag = id >> 9, within = id & 511;
    const int lane = within >> 3, j = within & 7;
    const int KPB = Kp >> 5;
    const int n_blk = frag / KPB, k_blk = frag % KPB;
    const int n = n_blk * 16 + (lane & 15);
    const int k = k_blk * 32 + (lane >> 4) * 8 + j;
    dst[id] = (k < K) ? f2bf(src[(size_t)k * N + n]) : (u16)0;
}

__global__ void embed_pad(const float* __restrict__ emb, u16* __restrict__ dst)
{
    int id = blockIdx.x * 256 + threadIdx.x;
    int v = id >> 7, k = id & 127;
    dst[id] = (k < E_) ? f2bf(emb[v * E_ + k]) : (u16)0;
}

// Fused phase p (independent sub-steps):
//   layer0: h0[p]   = tanh(embP[idx_p] @ Wx0 + h0[p-1] @ Wh0 + b0)   (if do0)
//   layer1: h1[p-1] = tanh(h0[p-1] @ Wx1 + h1[p-2] @ Wh1 + b1)       (if do1)
// Tile M=128 x N=128, BK=64; WAVE TILE 128x32 (wn = wave, 4-way n-split, NO m-split):
// each wave's B fragments are disjoint -> B direct-from-global (frag-packed, register-
// pipelined distance-1 ping-pong) adds ZERO duplicate L2 bytes (r13's sin: wm-pairs
// loaded identical B twice -> L2 cost ate the LDS savings; r11-vs-r13 algebra shows an
// L2 byte costs >=3x an LDS byte here). L2/block-iter = 32 KB (same as r11), LDS
// 96 -> 80 KB/block-iter, LDS footprint 64 -> 32 KB/block. A through swizzled LDS dbuf
// (r6-proven, 0 conflicts).
__global__ void __launch_bounds__(256, 2)
rnn_phase(const u16* __restrict__ embP, const int* __restrict__ idx,
          const u16* __restrict__ Wx0F, const u16* __restrict__ Wh0F, const float* __restrict__ b0,
          const u16* __restrict__ Wx1F, const u16* __restrict__ Wh1F, const float* __restrict__ b1,
          const u16* __restrict__ h0r, u16* __restrict__ h0w,
          const u16* __restrict__ h1r, u16* __restrict__ h1w,
          int do0, int do1)
{
    const int layer = blockIdx.y & 1;
    if (layer ? !do1 : !do0) return;

    __shared__ u16 As[2][128 * 64];   // 2 x 16 KB (A only)
    const int tid  = threadIdx.x;
    const int lane = tid & 63;
    const int wave = tid >> 6;
    const int m0 = blockIdx.x * 128;
    const int n0 = (blockIdx.y >> 1) * 128;

    const u16 *A1, *W1f, *A2, *W2f; const float* bias; u16* C; int K1; bool gather;
    if (layer == 0) { A1 = embP; W1f = Wx0F; K1 = 128;  gather = true;  A2 = h0r; W2f = Wh0F; bias = b0; C = h0w; }
    else            { A1 = h0r;  W1f = Wx1F; K1 = 1024; gather = false; A2 = h1r; W2f = Wh1F; bias = b1; C = h1w; }
    const int KB1  = K1 >> 6;           // 64-wide K blocks in the first segment (2 or 16)
    const int TOT  = KB1 + (U_ >> 6);   // 18 or 32 — always even
    const int KPB1 = K1 >> 5;
    const int KPB2 = U_ >> 5;

    // A staging: per wave rows [wave*32,+32) in 4 calls; lane -> row += lane>>3,
    // chunk lane&7, source col chunk swizzled (lane&7)^(row&7).
    const int r8 = lane >> 3;
    const int c8 = lane & 7;

    int gv[4];
    if (gather) {
#pragma unroll
        for (int cc = 0; cc < 4; cc++)
            gv[cc] = idx[(size_t)(m0 + wave * 32 + cc * 8 + r8) * T_];
    }

    const f32x4 z = {0.f, 0.f, 0.f, 0.f};
    f32x4 acc[8][2];   // 128 rows x 32 cols per wave
#pragma unroll
    for (int i = 0; i < 8; i++)
#pragma unroll
        for (int j = 0; j < 2; j++) acc[i][j] = z;

    // loop-invariant A fragment read offsets (u16 elems), inverse-swizzled; no wm term —
    // every wave scans the full 128-row A tile.
    const int l15 = lane & 15, q = lane >> 4, l7 = lane & 7;
    int offA[2][8];
#pragma unroll
    for (int kk = 0; kk < 2; kk++)
#pragma unroll
        for (int f = 0; f < 8; f++) {
            const int rA = f * 16 + l15;
            offA[kk][f] = rA * 64 + (((kk * 4 + q) ^ l7) * 8);
        }

    // B fragment bases: wave's n-frags are n_blk = n0/16 + wave*2 + f (f in 0..2) — disjoint
    const int nb = (n0 >> 4) + wave * 2;

    auto stage = [&](int u, int p) {
        u16* Ad = As[p] + wave * 2048;   // 32 rows x 64 elems
        if (u < KB1) {
            const int k0 = u * 64;
#pragma unroll
            for (int cc = 0; cc < 4; cc++) {
                const int row = wave * 32 + cc * 8 + r8;
                const int scw = (c8 ^ (row & 7)) * 8;
                const u16* ap = gather ? A1 + (size_t)gv[cc] * 128 + k0 + scw
                                       : A1 + (size_t)(m0 + row) * K1 + k0 + scw;
                load16(ap, Ad + cc * 512);
            }
        } else {
            const int k0 = (u - KB1) * 64;
#pragma unroll
            for (int cc = 0; cc < 4; cc++) {
                const int row = wave * 32 + cc * 8 + r8;
                const int scw = (c8 ^ (row & 7)) * 8;
                load16(A2 + (size_t)(m0 + row) * U_ + k0 + scw, Ad + cc * 512);
            }
        }
    };

    auto loadB = [&](int u, bf16x8 bdst[2][2]) {
        const u16* Wf; int kb, KPB;
        if (u < KB1) { Wf = W1f; kb = u * 2;         KPB = KPB1; }
        else         { Wf = W2f; kb = (u - KB1) * 2; KPB = KPB2; }
#pragma unroll
        for (int kk = 0; kk < 2; kk++)
#pragma unroll
            for (int f = 0; f < 2; f++)
                bdst[kk][f] = *reinterpret_cast<const bf16x8*>(
                    Wf + ((size_t)(nb + f) * KPB + kb + kk) * 512 + lane * 8);
    };

    auto compute = [&](const u16* Ab, bf16x8 b[2][2]) {
#pragma unroll
        for (int kk = 0; kk < 2; kk++) {
            bf16x8 a[8];
#pragma unroll
            for (int f = 0; f < 8; f++)
                a[f] = *reinterpret_cast<const bf16x8*>(Ab + offA[kk][f]);
#pragma unroll
            for (int i = 0; i < 8; i++)
#pragma unroll
                for (int j = 0; j < 2; j++)
                    acc[i][j] = __builtin_amdgcn_mfma_f32_16x16x32_bf16(a[i], b[kk][j], acc[i][j], 0, 0, 0);
        }
    };

    bf16x8 bA[2][2], bB[2][2];
    stage(0, 0);
    loadB(0, bA);

#pragma unroll 1
    for (int u = 0; u < TOT; u += 2) {
        __syncthreads();                        // As[0] ready; bA(u) long drained
        loadB(u + 1, bB);                       // in flight during compute(u)
        stage(u + 1, 1);
        compute(As[0], bA);
        __syncthreads();                        // As[1] + bB(u+1) drained
        if (u + 2 < TOT) {
            loadB(u + 2, bA);                   // in flight during compute(u+1)
            stage(u + 2, 0);
        }
        compute(As[1], bB);
    }

    // epilogue: bias + tanh, bf16 store (C/D map: col = lane&15, row = (lane>>4)*4 + reg)
#pragma unroll
    for (int j = 0; j < 2; j++) {
        const int col = n0 + wave * 32 + j * 16 + l15;
        const float bv = bias[col];
#pragma unroll
        for (int i = 0; i < 8; i++) {
#pragma unroll
            for (int r = 0; r < 4; r++) {
                const int row = m0 + i * 16 + (q << 2) + r;
                float x = acc[i][j][r] + bv;
                x = fminf(15.f, fmaxf(-15.f, x));
                float e = __expf(2.f * x);
                C[(size_t)row * U_ + col] = f2bf((e - 1.f) / (e + 1.f));
            }
        }
    }
}

// out[b] = sigmoid( dot(h1[b,:], Wfc) + bfc ), one wave per row; f32 out
__global__ void final_dense(const u16* __restrict__ h1, const float* __restrict__ Wfc,
                            const float* __restrict__ bfc, float* __restrict__ out)
{
    const int lane = threadIdx.x & 63;
    const int wave = threadIdx.x >> 6;
    const int row = blockIdx.x * 4 + wave;
    const u16* hp = h1 + (size_t)row * U_ + lane * 16;
    const float* wp = Wfc + lane * 16;
    float s = 0.f;
#pragma unroll
    for (int i = 0; i < 16; i++) s += bf2f(hp[i]) * wp[i];
#pragma unroll
    for (int off = 32; off; off >>= 1) s += __shfl_down(s, off);
    if (lane == 0) {
        float x = s + bfc[0];
        out[row] = 1.f / (1.f + __expf(-x));
    }
}

extern "C" void kernel_launch(void* const* d_in, const int* in_sizes, int n_in,
                              void* d_out, int out_size, void* d_ws, size_t ws_size,
                              hipStream_t stream)
{
    const int*   inputs = (const int*)d_in[0];
    const float* emb    = (const float*)d_in[1];
    const float* Wx0    = (const float*)d_in[2];
    const float* Wh0    = (const float*)d_in[3];
    const float* b0     = (const float*)d_in[4];
    const float* Wx1    = (const float*)d_in[5];
    const float* Wh1    = (const float*)d_in[6];
    const float* b1     = (const float*)d_in[7];
    const float* Wfc    = (const float*)d_in[8];
    const float* bfc    = (const float*)d_in[9];

    char* ws = (char*)d_ws;
    const size_t MB = 1 << 20;
    u16* h0b[2] = { (u16*)(ws + 0 * MB), (u16*)(ws + 8 * MB) };   // 8 MB each
    u16* h1b[2] = { (u16*)(ws + 16 * MB), (u16*)(ws + 24 * MB) };
    u16* embP = (u16*)(ws + 32 * MB);  // 2.56 MB
    u16* Wx0F = (u16*)(ws + 35 * MB);  // frag-packed [64 n_blk][4 k_blk]  256 KB
    u16* Wh0F = (u16*)(ws + 36 * MB);  // [64][32] 2 MB
    u16* Wx1F = (u16*)(ws + 38 * MB);  // 2 MB
    u16* Wh1F = (u16*)(ws + 40 * MB);  // ..42 MB

    // phase 0 reads h0[-1] from h0b[1]; phase 1 reads h1[-1] from h1b[1]
    hipMemsetAsync(h0b[1], 0, 8 * MB, stream);
    hipMemsetAsync(h1b[1], 0, 8 * MB, stream);

    embed_pad<<<V_ * 128 / 256, 256, 0, stream>>>(emb, embP);
    frag_pack<<<(U_ / 16) * (128 / 32) * 512 / 256, 256, 0, stream>>>(Wx0, Wx0F, E_, U_, 128);
    frag_pack<<<(U_ / 16) * (U_ / 32) * 512 / 256, 256, 0, stream>>>(Wh0, Wh0F, U_, U_, U_);
    frag_pack<<<(U_ / 16) * (U_ / 32) * 512 / 256, 256, 0, stream>>>(Wx1, Wx1F, U_, U_, U_);
    frag_pack<<<(U_ / 16) * (U_ / 32) * 512 / 256, 256, 0, stream>>>(Wh1, Wh1F, U_, U_, U_);

    // phase p: layer0 writes h0[p] -> h0b[p&1], reads h0[p-1] -> h0b[(p&1)^1];
    //          layer1 writes h1[p-1] -> h1b[(p&1)^1], reads h1[p-2] -> h1b[p&1]
    dim3 grid(B_ / 128, 2 * (U_ / 128));   // 32 x 16 = 512 blocks -> 2/CU, all resident
    for (int p = 0; p <= T_; ++p) {
        const int e = p & 1;
        rnn_phase<<<grid, 256, 0, stream>>>(embP, inputs + p,
                                            Wx0F, Wh0F, b0, Wx1F, Wh1F, b1,
                                            h0b[e ^ 1], h0b[e], h1b[e], h1b[e ^ 1],
                                            (int)(p < T_), (int)(p >= 1));
    }
    // h1[79] written at phase 80 into h1b[(80&1)^1] = h1b[1]
    final_dense<<<B_ / 4, 256, 0, stream>>>(h1b[1], Wfc, bfc, (float*)d_out);
}

// Round 15
// 3047.948 us; speedup vs baseline: 1.3890x; 1.0069x over previous
//
#include <hip/hip_runtime.h>
#include <stdint.h>

#define B_ 4096
#define T_ 80
#define E_ 100
#define V_ 10000
#define U_ 1024

typedef unsigned short u16;
typedef __attribute__((ext_vector_type(8))) __bf16 bf16x8;
typedef __attribute__((ext_vector_type(4))) float f32x4;

__device__ __forceinline__ float bf2f(u16 u) {
    union { unsigned int i; float f; } v; v.i = ((unsigned int)u) << 16; return v.f;
}
__device__ __forceinline__ u16 f2bf(float f) {
    union { float f; unsigned int i; } v; v.f = f;
    unsigned int x = v.i;
    return (u16)((x + 0x7fffu + ((x >> 16) & 1u)) >> 16);
}

// async global->LDS, 16 B per lane; LDS dest = wave-uniform base + lane*16 (m104 semantics).
__device__ __forceinline__ void load16(const void* g, void* l) {
    __builtin_amdgcn_global_load_lds(
        (__attribute__((address_space(1))) void*)(uintptr_t)g,
        (__attribute__((address_space(3))) void*)(uint32_t)(uintptr_t)l,
        16, 0, 0);
}

// Pack weight src (f32, [K][N] row-major) into MFMA-B-fragment order, bf16, K padded to Kp:
// frag (n_blk, k_blk) = 1 KB holding lane l's 8 elems at [n = n_blk*16 + (l&15)]
// [k = k_blk*32 + (l>>4)*8 + j]. A wave's B-frag load = one coalesced global_load_dwordx4.
__global__ void frag_pack(const float* __restrict__ src, u16* __restrict__ dst,
                          int K, int N, int Kp)
{
    const int id = blockIdx.x * 256 + threadIdx.x;    // over N/16 * Kp/32 * 512 elems
    const int frag = id >> 9, within = id & 511;
    const int lane = within >> 3, j = within & 7;
    const int KPB = Kp >> 5;
    const int n_blk = frag / KPB, k_blk = frag % KPB;
    const int n = n_blk * 16 + (lane & 15);
    const int k = k_blk * 32 + (lane >> 4) * 8 + j;
    dst[id] = (k < K) ? f2bf(src[(size_t)k * N + n]) : (u16)0;
}

__global__ void embed_pad(const float* __restrict__ emb, u16* __restrict__ dst)
{
    int id = blockIdx.x * 256 + threadIdx.x;
    int v = id >> 7, k = id & 127;
    dst[id] = (k < E_) ? f2bf(emb[v * E_ + k]) : (u16)0;
}

// Fused phase p (independent sub-steps):
//   layer0: h0[p]   = tanh(embP[idx_p] @ Wx0 + h0[p-1] @ Wh0 + b0)   (if do0)
//   layer1: h1[p-1] = tanh(h0[p-1] @ Wx1 + h1[p-2] @ Wh1 + b1)       (if do1)
// r14 structure (tile M=128 x N=128, BK=64, wave 128x32, A via swizzled LDS dbuf,
// B direct-from-global frag-packed + register-pipelined distance 1, 0 conflicts).
// NEW (r14 post-mortem): LAYER-BALANCED FLAT GRID. Old (32,32) grid put two layer0
// blocks (18 iters) on some CUs and two layer1 blocks (32 iters) on others ->
// critical path 64 iters vs mean 50 (~28% idle). Flat bids: 0..255 = all layer0,
// 256..511 = all layer1; round-robin dispatch gives each CU ~one of each.
__global__ void __launch_bounds__(256, 2)
rnn_phase(const u16* __restrict__ embP, const int* __restrict__ idx,
          const u16* __restrict__ Wx0F, const u16* __restrict__ Wh0F, const float* __restrict__ b0,
          const u16* __restrict__ Wx1F, const u16* __restrict__ Wh1F, const float* __restrict__ b1,
          const u16* __restrict__ h0r, u16* __restrict__ h0w,
          const u16* __restrict__ h1r, u16* __restrict__ h1w,
          int do0, int do1)
{
    const int bid   = blockIdx.x;
    const int layer = bid >> 8;            // 0..255 -> layer0, 256..511 -> layer1
    if (layer ? !do1 : !do0) return;
    const int kk_   = bid & 255;
    const int m0 = (kk_ >> 3) * 128;       // 32 m-tiles
    const int n0 = (kk_ & 7) * 128;        // 8 n-tiles

    __shared__ u16 As[2][128 * 64];   // 2 x 16 KB (A only)
    const int tid  = threadIdx.x;
    const int lane = tid & 63;
    const int wave = tid >> 6;

    const u16 *A1, *W1f, *A2, *W2f; const float* bias; u16* C; int K1; bool gather;
    if (layer == 0) { A1 = embP; W1f = Wx0F; K1 = 128;  gather = true;  A2 = h0r; W2f = Wh0F; bias = b0; C = h0w; }
    else            { A1 = h0r;  W1f = Wx1F; K1 = 1024; gather = false; A2 = h1r; W2f = Wh1F; bias = b1; C = h1w; }
    const int KB1  = K1 >> 6;           // 64-wide K blocks in the first segment (2 or 16)
    const int TOT  = KB1 + (U_ >> 6);   // 18 or 32 — always even
    const int KPB1 = K1 >> 5;
    const int KPB2 = U_ >> 5;

    // A staging: per wave rows [wave*32,+32) in 4 calls; lane -> row += lane>>3,
    // chunk lane&7, source col chunk swizzled (lane&7)^(row&7).
    const int r8 = lane >> 3;
    const int c8 = lane & 7;

    int gv[4];
    if (gather) {
#pragma unroll
        for (int cc = 0; cc < 4; cc++)
            gv[cc] = idx[(size_t)(m0 + wave * 32 + cc * 8 + r8) * T_];
    }

    const f32x4 z = {0.f, 0.f, 0.f, 0.f};
    f32x4 acc[8][2];   // 128 rows x 32 cols per wave
#pragma unroll
    for (int i = 0; i < 8; i++)
#pragma unroll
        for (int j = 0; j < 2; j++) acc[i][j] = z;

    // loop-invariant A fragment read offsets (u16 elems), inverse-swizzled; no wm term —
    // every wave scans the full 128-row A tile.
    const int l15 = lane & 15, q = lane >> 4, l7 = lane & 7;
    int offA[2][8];
#pragma unroll
    for (int kk = 0; kk < 2; kk++)
#pragma unroll
        for (int f = 0; f < 8; f++) {
            const int rA = f * 16 + l15;
            offA[kk][f] = rA * 64 + (((kk * 4 + q) ^ l7) * 8);
        }

    // B fragment bases: wave's n-frags are n_blk = n0/16 + wave*2 + f (f in 0..1) — disjoint
    const int nb = (n0 >> 4) + wave * 2;

    auto stage = [&](int u, int p) {
        u16* Ad = As[p] + wave * 2048;   // 32 rows x 64 elems
        if (u < KB1) {
            const int k0 = u * 64;
#pragma unroll
            for (int cc = 0; cc < 4; cc++) {
                const int row = wave * 32 + cc * 8 + r8;
                const int scw = (c8 ^ (row & 7)) * 8;
                const u16* ap = gather ? A1 + (size_t)gv[cc] * 128 + k0 + scw
                                       : A1 + (size_t)(m0 + row) * K1 + k0 + scw;
                load16(ap, Ad + cc * 512);
            }
        } else {
            const int k0 = (u - KB1) * 64;
#pragma unroll
            for (int cc = 0; cc < 4; cc++) {
                const int row = wave * 32 + cc * 8 + r8;
                const int scw = (c8 ^ (row & 7)) * 8;
                load16(A2 + (size_t)(m0 + row) * U_ + k0 + scw, Ad + cc * 512);
            }
        }
    };

    auto loadB = [&](int u, bf16x8 bdst[2][2]) {
        const u16* Wf; int kb, KPB;
        if (u < KB1) { Wf = W1f; kb = u * 2;         KPB = KPB1; }
        else         { Wf = W2f; kb = (u - KB1) * 2; KPB = KPB2; }
#pragma unroll
        for (int kk = 0; kk < 2; kk++)
#pragma unroll
            for (int f = 0; f < 2; f++)
                bdst[kk][f] = *reinterpret_cast<const bf16x8*>(
                    Wf + ((size_t)(nb + f) * KPB + kb + kk) * 512 + lane * 8);
    };

    auto compute = [&](const u16* Ab, bf16x8 b[2][2]) {
#pragma unroll
        for (int kk = 0; kk < 2; kk++) {
            bf16x8 a[8];
#pragma unroll
            for (int f = 0; f < 8; f++)
                a[f] = *reinterpret_cast<const bf16x8*>(Ab + offA[kk][f]);
#pragma unroll
            for (int i = 0; i < 8; i++)
#pragma unroll
                for (int j = 0; j < 2; j++)
                    acc[i][j] = __builtin_amdgcn_mfma_f32_16x16x32_bf16(a[i], b[kk][j], acc[i][j], 0, 0, 0);
        }
    };

    bf16x8 bA[2][2], bB[2][2];
    stage(0, 0);
    loadB(0, bA);

#pragma unroll 1
    for (int u = 0; u < TOT; u += 2) {
        __syncthreads();                        // As[0] ready; bA(u) long drained
        loadB(u + 1, bB);                       // in flight during compute(u)
        stage(u + 1, 1);
        compute(As[0], bA);
        __syncthreads();                        // As[1] + bB(u+1) drained
        if (u + 2 < TOT) {
            loadB(u + 2, bA);                   // in flight during compute(u+1)
            stage(u + 2, 0);
        }
        compute(As[1], bB);
    }

    // epilogue: bias + tanh, bf16 store (C/D map: col = lane&15, row = (lane>>4)*4 + reg)
#pragma unroll
    for (int j = 0; j < 2; j++) {
        const int col = n0 + wave * 32 + j * 16 + l15;
        const float bv = bias[col];
#pragma unroll
        for (int i = 0; i < 8; i++) {
#pragma unroll
            for (int r = 0; r < 4; r++) {
                const int row = m0 + i * 16 + (q << 2) + r;
                float x = acc[i][j][r] + bv;
                x = fminf(15.f, fmaxf(-15.f, x));
                float e = __expf(2.f * x);
                C[(size_t)row * U_ + col] = f2bf((e - 1.f) / (e + 1.f));
            }
        }
    }
}

// out[b] = sigmoid( dot(h1[b,:], Wfc) + bfc ), one wave per row; f32 out
__global__ void final_dense(const u16* __restrict__ h1, const float* __restrict__ Wfc,
                            const float* __restrict__ bfc, float* __restrict__ out)
{
    const int lane = threadIdx.x & 63;
    const int wave = threadIdx.x >> 6;
    const int row = blockIdx.x * 4 + wave;
    const u16* hp = h1 + (size_t)row * U_ + lane * 16;
    const float* wp = Wfc + lane * 16;
    float s = 0.f;
#pragma unroll
    for (int i = 0; i < 16; i++) s += bf2f(hp[i]) * wp[i];
#pragma unroll
    for (int off = 32; off; off >>= 1) s += __shfl_down(s, off);
    if (lane == 0) {
        float x = s + bfc[0];
        out[row] = 1.f / (1.f + __expf(-x));
    }
}

extern "C" void kernel_launch(void* const* d_in, const int* in_sizes, int n_in,
                              void* d_out, int out_size, void* d_ws, size_t ws_size,
                              hipStream_t stream)
{
    const int*   inputs = (const int*)d_in[0];
    const float* emb    = (const float*)d_in[1];
    const float* Wx0    = (const float*)d_in[2];
    const float* Wh0    = (const float*)d_in[3];
    const float* b0     = (const float*)d_in[4];
    const float* Wx1    = (const float*)d_in[5];
    const float* Wh1    = (const float*)d_in[6];
    const float* b1     = (const float*)d_in[7];
    const float* Wfc    = (const float*)d_in[8];
    const float* bfc    = (const float*)d_in[9];

    char* ws = (char*)d_ws;
    const size_t MB = 1 << 20;
    u16* h0b[2] = { (u16*)(ws + 0 * MB), (u16*)(ws + 8 * MB) };   // 8 MB each
    u16* h1b[2] = { (u16*)(ws + 16 * MB), (u16*)(ws + 24 * MB) };
    u16* embP = (u16*)(ws + 32 * MB);  // 2.56 MB
    u16* Wx0F = (u16*)(ws + 35 * MB);  // frag-packed [64 n_blk][4 k_blk]  256 KB
    u16* Wh0F = (u16*)(ws + 36 * MB);  // [64][32] 2 MB
    u16* Wx1F = (u16*)(ws + 38 * MB);  // 2 MB
    u16* Wh1F = (u16*)(ws + 40 * MB);  // ..42 MB

    // phase 0 reads h0[-1] from h0b[1]; phase 1 reads h1[-1] from h1b[1]
    hipMemsetAsync(h0b[1], 0, 8 * MB, stream);
    hipMemsetAsync(h1b[1], 0, 8 * MB, stream);

    embed_pad<<<V_ * 128 / 256, 256, 0, stream>>>(emb, embP);
    frag_pack<<<(U_ / 16) * (128 / 32) * 512 / 256, 256, 0, stream>>>(Wx0, Wx0F, E_, U_, 128);
    frag_pack<<<(U_ / 16) * (U_ / 32) * 512 / 256, 256, 0, stream>>>(Wh0, Wh0F, U_, U_, U_);
    frag_pack<<<(U_ / 16) * (U_ / 32) * 512 / 256, 256, 0, stream>>>(Wx1, Wx1F, U_, U_, U_);
    frag_pack<<<(U_ / 16) * (U_ / 32) * 512 / 256, 256, 0, stream>>>(Wh1, Wh1F, U_, U_, U_);

    // phase p: layer0 writes h0[p] -> h0b[p&1], reads h0[p-1] -> h0b[(p&1)^1];
    //          layer1 writes h1[p-1] -> h1b[(p&1)^1], reads h1[p-2] -> h1b[p&1]
    dim3 grid(512);   // flat: bids 0..255 layer0, 256..511 layer1 (one of each per CU)
    for (int p = 0; p <= T_; ++p) {
        const int e = p & 1;
        rnn_phase<<<grid, 256, 0, stream>>>(embP, inputs + p,
                                            Wx0F, Wh0F, b0, Wx1F, Wh1F, b1,
                                            h0b[e ^ 1], h0b[e], h1b[e], h1b[e ^ 1],
                                            (int)(p < T_), (int)(p >= 1));
    }
    // h1[79] written at phase 80 into h1b[(80&1)^1] = h1b[1]
    final_dense<<<B_ / 4, 256, 0, stream>>>(h1b[1], Wfc, bfc, (float*)d_out);
}